// Round 5
// baseline (190.899 us; speedup 1.0000x reference)
//
#include <hip/hip_runtime.h>
#include <hip/hip_bf16.h>

typedef __bf16 bf16_t;
typedef __bf16 bf16x8 __attribute__((ext_vector_type(8)));
typedef __bf16 bf16x4 __attribute__((ext_vector_type(4)));
typedef float  f32x4  __attribute__((ext_vector_type(4)));

#define D  128
#define BM 128

// LDS element-index swizzle: XOR multiples of 8 elems (16B) keep 4/8-elem groups intact.
__device__ __forceinline__ int swz(int r, int c) {
    return (r * D + c) ^ ((r & 7) << 3);
}

// Pack weights in MFMA B-fragment lane order:
//   ws[(((s*4+kk)*8+n)*64 + lane)*8 + j] = Wt_s[n*16 + (lane&15)][kk*32 + (lane>>4)*8 + j]
// where Wt_s = W1^T slice s (s<3) or W2^T (s==3). Each fragment is 1KB contiguous.
__global__ void prep_weights_kernel(const float* __restrict__ W1,
                                    const float* __restrict__ W2,
                                    bf16_t* __restrict__ ws) {
    int t = blockIdx.x * 256 + threadIdx.x;     // 8192 threads, 16B each
    int lane = t & 63, g = t >> 6;
    int n = g & 7, kk = (g >> 3) & 3, s = g >> 5;
    int row = n * 16 + (lane & 15);
    int k0 = kk * 32 + (lane >> 4) * 8;
    bf16x8 v;
#pragma unroll
    for (int j = 0; j < 8; j++) {
        int k = k0 + j;
        float f = (s < 3) ? W1[(s * 128 + k) * 128 + row] : W2[k * 128 + row];
        v[j] = (bf16_t)f;
    }
    *(bf16x8*)(ws + t * 8) = v;
}

__global__ __launch_bounds__(256, 3)
void fused_edge_mlp_kernel(const float* __restrict__ x,
                           const float* __restrict__ ea,
                           const int* __restrict__ ei,
                           const bf16_t* __restrict__ ws,
                           const float* __restrict__ b1,
                           const float* __restrict__ b2,
                           float* __restrict__ out,
                           int E) {
    __shared__ __align__(16) bf16_t Ab[BM * D];   // 32 KB: wave-private 32-row A/H chunks

    const int tid  = threadIdx.x;
    const int lane = tid & 63;
    const int wv   = tid >> 6;        // wave owns rows [wv*32, wv*32+32)
    const int col0 = lane & 15;
    const int krow = lane >> 4;       // 0..3
    const int l31  = lane & 31;
    const int half = lane >> 5;       // 0/1
    const int e0   = blockIdx.x * BM;

    // per-lane edge indices for this wave's 32 rows (lanes 32..63 duplicate 0..31)
    const int erL  = min(e0 + wv * 32 + l31, E - 1);
    const int sidx = ei[erL];
    const int didx = ei[E + erL];

    f32x4 abuf[16];

    // ---- prologue: gather x[src] (each instr: 32 lanes span one contiguous 512B row) ----
#pragma unroll
    for (int j = 0; j < 16; j++) {
        int r = j * 2 + half;                       // local row 0..31
        int g = __shfl(sidx, r);
        abuf[j] = *(const f32x4*)(x + (long long)g * D + l31 * 4);
    }
    float bias1[8], bias2[8];
#pragma unroll
    for (int n = 0; n < 8; n++) { bias1[n] = b1[n*16 + col0]; bias2[n] = b2[n*16 + col0]; }
#pragma unroll
    for (int j = 0; j < 16; j++) {
        int r = j * 2 + half;
        f32x4 v = abuf[j];
        bf16x4 hv = { (bf16_t)v.x, (bf16_t)v.y, (bf16_t)v.z, (bf16_t)v.w };
        *(bf16x4*)&Ab[swz(wv * 32 + r, l31 * 4)] = hv;
    }

    f32x4 acc[2][8];
#pragma unroll
    for (int m = 0; m < 2; m++)
#pragma unroll
        for (int n = 0; n < 8; n++) acc[m][n] = (f32x4){0.f, 0.f, 0.f, 0.f};

    // ---- phases: 0=x[src]·W1a  1=x[dst]·W1b  2=ea·W1c  3=h·W2 ; NO barriers ----
#pragma unroll
    for (int p = 0; p < 4; p++) {
        // issue next phase's A gathers (hidden under this phase's MFMA + B loads)
        if (p < 2) {
#pragma unroll
            for (int j = 0; j < 16; j++) {
                int r = j * 2 + half;
                const float* rp;
                if (p == 0) { int g = __shfl(didx, r); rp = x + (long long)g * D; }
                else        { int e = min(e0 + wv * 32 + r, E - 1); rp = ea + (long long)e * D; }
                abuf[j] = *(const f32x4*)(rp + l31 * 4);
            }
        }

        // MFMA loop; B-fragments stream from packed global (L2-hot, 1KB coalesced per instr)
#pragma unroll
        for (int kk = 0; kk < 4; kk++) {
            bf16x8 a0 = *(const bf16x8*)&Ab[swz(wv*32 +      col0, kk*32 + krow*8)];
            bf16x8 a1 = *(const bf16x8*)&Ab[swz(wv*32 + 16 + col0, kk*32 + krow*8)];
            const bf16_t* bbase = ws + ((p * 4 + kk) * 8 * 64 + lane) * 8;
#pragma unroll
            for (int n = 0; n < 8; n++) {
                bf16x8 b = *(const bf16x8*)(bbase + n * 512);
                acc[0][n] = __builtin_amdgcn_mfma_f32_16x16x32_bf16(a0, b, acc[0][n], 0, 0, 0);
                acc[1][n] = __builtin_amdgcn_mfma_f32_16x16x32_bf16(a1, b, acc[1][n], 0, 0, 0);
            }
        }

        // write next A into my chunk (wave-private; per-wave LDS ordering guarantees
        // these writes follow this phase's ds_reads)
        if (p < 2) {
#pragma unroll
            for (int j = 0; j < 16; j++) {
                int r = j * 2 + half;
                f32x4 v = abuf[j];
                bf16x4 hv = { (bf16_t)v.x, (bf16_t)v.y, (bf16_t)v.z, (bf16_t)v.w };
                *(bf16x4*)&Ab[swz(wv * 32 + r, l31 * 4)] = hv;
            }
        }
        // h = relu(acc + b1) -> my chunk (GEMM2's A), reset acc
        if (p == 2) {
#pragma unroll
            for (int m = 0; m < 2; m++)
#pragma unroll
                for (int n = 0; n < 8; n++)
#pragma unroll
                    for (int ri = 0; ri < 4; ri++) {
                        float hv = fmaxf(acc[m][n][ri] + bias1[n], 0.f);
                        Ab[swz(wv*32 + m*16 + krow*4 + ri, n*16 + col0)] = (bf16_t)hv;
                    }
#pragma unroll
            for (int m = 0; m < 2; m++)
#pragma unroll
                for (int n = 0; n < 8; n++) acc[m][n] = (f32x4){0.f, 0.f, 0.f, 0.f};
        }
    }

    // ---- epilogue: out = relu(acc + b2) ----
#pragma unroll
    for (int m = 0; m < 2; m++)
#pragma unroll
        for (int n = 0; n < 8; n++)
#pragma unroll
            for (int ri = 0; ri < 4; ri++) {
                int row = wv*32 + m*16 + krow*4 + ri;
                int e = e0 + row;
                if (e < E) out[(long long)e * D + n*16 + col0] = fmaxf(acc[m][n][ri] + bias2[n], 0.f);
            }
}

extern "C" void kernel_launch(void* const* d_in, const int* in_sizes, int n_in,
                              void* d_out, int out_size, void* d_ws, size_t ws_size,
                              hipStream_t stream) {
    const float* x  = (const float*)d_in[0];
    const float* ea = (const float*)d_in[1];
    const int*   ei = (const int*)d_in[2];
    const float* W1 = (const float*)d_in[3];
    const float* b1 = (const float*)d_in[4];
    const float* W2 = (const float*)d_in[5];
    const float* b2 = (const float*)d_in[6];
    float* out = (float*)d_out;

    const int E = in_sizes[1] / D;

    bf16_t* wsl = (bf16_t*)d_ws;    // 4 slices x 4 kk x 8 n x 1KB = 128 KB packed fragments

    prep_weights_kernel<<<32, 256, 0, stream>>>(W1, W2, wsl);

    int nblocks = (E + BM - 1) / BM;    // 3125 for E=400000
    fused_edge_mlp_kernel<<<nblocks, 256, 0, stream>>>(x, ea, ei, wsl, b1, b2, out, E);
}

// Round 6
// 169.606 us; speedup vs baseline: 1.1255x; 1.1255x over previous
//
#include <hip/hip_runtime.h>
#include <hip/hip_bf16.h>

typedef __bf16 bf16_t;
typedef __bf16 bf16x8 __attribute__((ext_vector_type(8)));
typedef float  f32x4  __attribute__((ext_vector_type(4)));

#define D  128
#define BM 64   // 4 waves x 16 rows

// LDS element-index swizzle: XOR multiples of 8 elems (16B) keep 8-elem groups intact.
__device__ __forceinline__ int swz(int r, int c) {
    return (r * D + c) ^ ((r & 7) << 3);
}

// Weights as 4 slice-major tiles [s][n][k], bf16, transposed:
//  s<3:  ws[s*16384 + n*128 + k] = W1[(s*128+k)*128 + n]
//  s==3: ws[3*16384 + n*128 + k] = W2[k*128 + n]
__global__ void prep_weights_kernel(const float* __restrict__ W1,
                                    const float* __restrict__ W2,
                                    bf16_t* __restrict__ ws) {
    int t = blockIdx.x * 256 + threadIdx.x;       // 65536 total
    int s = t >> 14, r = t & 16383;
    int n = r >> 7, k = r & 127;
    float v = (s < 3) ? W1[(s * 128 + k) * 128 + n] : W2[k * 128 + n];
    ws[t] = (bf16_t)v;
}

__global__ __launch_bounds__(256, 3)
void fused_edge_mlp_kernel(const float* __restrict__ x,
                           const float* __restrict__ ea,
                           const int* __restrict__ ei,
                           const bf16_t* __restrict__ ws,
                           const float* __restrict__ b1,
                           const float* __restrict__ b2,
                           float* __restrict__ out,
                           int E) {
    __shared__ __align__(16) bf16_t Bb[D * D];    // 32 KB: current weight slice (shared)
    __shared__ __align__(16) bf16_t Hb[BM * D];   // 16 KB: hidden tile (wave-private chunks)

    const int tid  = threadIdx.x;
    const int lane = tid & 63;
    const int wv   = tid >> 6;        // wave owns rows [wv*16, wv*16+16)
    const int col0 = lane & 15;
    const int krow = lane >> 4;       // 0..3
    const int e0   = blockIdx.x * BM;

    // this lane's fragment row and its edge indices (4 lanes share a row -> broadcast)
    const int erL  = min(e0 + wv * 16 + col0, E - 1);
    const int sidx = ei[erL];
    const int didx = ei[E + erL];

    // B staging: instr j covers rows [j*16, j*16+16), 16B per thread (1KB contiguous)
    const int brow_t = tid >> 4;          // 0..15
    const int bslot  = (tid & 15) * 8;    // element offset

    f32x4  afA[8];      // this lane's 16-row-tile fragment: 8 f32 per kk (2 x f32x4)
    bf16x8 bnext[8];

    // ---- prologue: B slice 0 regs + x[src] fragment loads ----
    {
        const bf16_t* base = ws;
#pragma unroll
        for (int j = 0; j < 8; j++)
            bnext[j] = *(const bf16x8*)(base + (j * 16 + brow_t) * 128 + bslot);
    }
    {
        const float* rp = x + (long long)sidx * D + krow * 8;
#pragma unroll
        for (int kk = 0; kk < 4; kk++) {
            afA[kk*2]   = *(const f32x4*)(rp + kk*32);
            afA[kk*2+1] = *(const f32x4*)(rp + kk*32 + 4);
        }
    }
    float bias1[8], bias2[8];
#pragma unroll
    for (int n = 0; n < 8; n++) { bias1[n] = b1[n*16 + col0]; bias2[n] = b2[n*16 + col0]; }

#pragma unroll
    for (int j = 0; j < 8; j++)
        *(bf16x8*)&Bb[swz(j * 16 + brow_t, bslot)] = bnext[j];

    f32x4 acc[8];
#pragma unroll
    for (int n = 0; n < 8; n++) acc[n] = (f32x4){0.f, 0.f, 0.f, 0.f};

    __syncthreads();    // Bb slice 0 ready

    // ---- phases: 0=x[src]·W1a  1=x[dst]·W1b  2=ea·W1c  3=h·W2 ----
#pragma unroll
    for (int p = 0; p < 4; p++) {
        // prefetch next weight slice into regs (hidden under this phase's MFMA)
        if (p < 3) {
            const bf16_t* base = ws + (p + 1) * 16384;
#pragma unroll
            for (int j = 0; j < 8; j++)
                bnext[j] = *(const bf16x8*)(base + (j * 16 + brow_t) * 128 + bslot);
        }

        // convert this phase's A fragments (waits on afA loads), then reuse afA
        bf16x8 a_cur[4];
        if (p < 3) {
#pragma unroll
            for (int kk = 0; kk < 4; kk++) {
                f32x4 lo = afA[kk*2], hi = afA[kk*2+1];
                a_cur[kk] = (bf16x8){ (bf16_t)lo.x,(bf16_t)lo.y,(bf16_t)lo.z,(bf16_t)lo.w,
                                      (bf16_t)hi.x,(bf16_t)hi.y,(bf16_t)hi.z,(bf16_t)hi.w };
            }
        }
        // issue next phase's A fragment loads (fly during this phase's MFMA)
        if (p < 2) {
            const float* rp = (p == 0) ? (x + (long long)didx * D + krow * 8)
                                       : (ea + (long long)erL * D + krow * 8);
#pragma unroll
            for (int kk = 0; kk < 4; kk++) {
                afA[kk*2]   = *(const f32x4*)(rp + kk*32);
                afA[kk*2+1] = *(const f32x4*)(rp + kk*32 + 4);
            }
        }

        // MFMA for this phase
#pragma unroll
        for (int kk = 0; kk < 4; kk++) {
            bf16x8 a;
            if (p < 3) a = a_cur[kk];
            else       a = *(const bf16x8*)&Hb[swz(wv*16 + col0, kk*32 + krow*8)];
#pragma unroll
            for (int n = 0; n < 8; n++) {
                bf16x8 b = *(const bf16x8*)&Bb[swz(n*16 + col0, kk*32 + krow*8)];
                acc[n] = __builtin_amdgcn_mfma_f32_16x16x32_bf16(a, b, acc[n], 0, 0, 0);
            }
        }

        // h = relu(acc + b1) -> my wave's Hb chunk (per-wave LDS ordering suffices)
        if (p == 2) {
#pragma unroll
            for (int n = 0; n < 8; n++)
#pragma unroll
                for (int ri = 0; ri < 4; ri++) {
                    float hv = fmaxf(acc[n][ri] + bias1[n], 0.f);
                    Hb[swz(wv*16 + krow*4 + ri, n*16 + col0)] = (bf16_t)hv;
                }
#pragma unroll
            for (int n = 0; n < 8; n++) acc[n] = (f32x4){0.f, 0.f, 0.f, 0.f};
        }

        // rotate weight slice (the only block-wide sync)
        if (p < 3) {
            __syncthreads();
#pragma unroll
            for (int j = 0; j < 8; j++)
                *(bf16x8*)&Bb[swz(j * 16 + brow_t, bslot)] = bnext[j];
            __syncthreads();
        }
    }

    // ---- epilogue: out = relu(acc + b2) ----
#pragma unroll
    for (int n = 0; n < 8; n++)
#pragma unroll
        for (int ri = 0; ri < 4; ri++) {
            int row = wv*16 + krow*4 + ri;
            int e = e0 + row;
            if (e < E) out[(long long)e * D + n*16 + col0] = fmaxf(acc[n][ri] + bias2[n], 0.f);
        }
}

extern "C" void kernel_launch(void* const* d_in, const int* in_sizes, int n_in,
                              void* d_out, int out_size, void* d_ws, size_t ws_size,
                              hipStream_t stream) {
    const float* x  = (const float*)d_in[0];
    const float* ea = (const float*)d_in[1];
    const int*   ei = (const int*)d_in[2];
    const float* W1 = (const float*)d_in[3];
    const float* b1 = (const float*)d_in[4];
    const float* W2 = (const float*)d_in[5];
    const float* b2 = (const float*)d_in[6];
    float* out = (float*)d_out;

    const int E = in_sizes[1] / D;

    bf16_t* wsl = (bf16_t*)d_ws;    // 4 slices x 128x128 bf16 = 128 KB

    prep_weights_kernel<<<256, 256, 0, stream>>>(W1, W2, wsl);

    int nblocks = (E + BM - 1) / BM;    // 6250 for E=400000
    fused_edge_mlp_kernel<<<nblocks, 256, 0, stream>>>(x, ea, ei, wsl, b1, b2, out, E);
}

// Round 7
// 160.499 us; speedup vs baseline: 1.1894x; 1.0567x over previous
//
#include <hip/hip_runtime.h>
#include <hip/hip_bf16.h>

typedef __bf16 bf16_t;
typedef __bf16 bf16x8 __attribute__((ext_vector_type(8)));
typedef __bf16 bf16x4 __attribute__((ext_vector_type(4)));
typedef float  f32x4  __attribute__((ext_vector_type(4)));

#define D  128
#define BM 64   // 4 waves x 16 rows

// LDS element-index swizzle: XOR multiples of 8 elems (16B) keep 8-elem groups intact.
__device__ __forceinline__ int swz(int r, int c) {
    return (r * D + c) ^ ((r & 7) << 3);
}

// Weights as 4 slice-major tiles [s][n][k], bf16, transposed:
//  s<3:  ws[s*16384 + n*128 + k] = W1[(s*128+k)*128 + n]
//  s==3: ws[3*16384 + n*128 + k] = W2[k*128 + n]
__global__ void prep_weights_kernel(const float* __restrict__ W1,
                                    const float* __restrict__ W2,
                                    bf16_t* __restrict__ ws) {
    int t = blockIdx.x * 256 + threadIdx.x;       // 65536 total
    int s = t >> 14, r = t & 16383;
    int n = r >> 7, k = r & 127;
    float v = (s < 3) ? W1[(s * 128 + k) * 128 + n] : W2[k * 128 + n];
    ws[t] = (bf16_t)v;
}

__global__ __launch_bounds__(256, 3)
void fused_edge_mlp_kernel(const float* __restrict__ x,
                           const float* __restrict__ ea,
                           const int* __restrict__ ei,
                           const bf16_t* __restrict__ ws,
                           const float* __restrict__ b1,
                           const float* __restrict__ b2,
                           float* __restrict__ out,
                           int E) {
    __shared__ __align__(16) bf16_t Bb[D * D];    // 32 KB: current weight slice (shared)
    __shared__ __align__(16) bf16_t Ab[BM * D];   // 16 KB: A/H tile (wave-private 16-row chunks)

    const int tid  = threadIdx.x;
    const int lane = tid & 63;
    const int wv   = tid >> 6;
    const int col0 = lane & 15;
    const int krow = lane >> 4;       // 0..3
    const int l31  = lane & 31;
    const int half = lane >> 5;       // 0/1
    const int e0   = blockIdx.x * BM;
    const int r0   = wv * 16;         // wave's first local row

    // lane l (l31&15) holds edge indices for local row (l31&15) of this wave's chunk
    const int erI  = min(e0 + r0 + (l31 & 15), E - 1);
    const int sidx = ei[erI];
    const int didx = ei[E + erI];

    // B staging: wave-instr j covers 4 consecutive rows = 1KB contiguous
    const int brow_t = tid >> 4;          // 0..15
    const int bslot  = (tid & 15) * 8;    // element offset

    f32x4  bufA[8];   // src, later reused for ea
    f32x4  bufD[8];   // dst (lives until phase q1 end)
    bf16x8 bnext[8];

    // ---- prologue: issue B slice0 + src gathers + dst gathers ----
#pragma unroll
    for (int j = 0; j < 8; j++)
        bnext[j] = *(const bf16x8*)(ws + (j * 16 + brow_t) * 128 + bslot);
    // coalesced gathers: instr j = rows (j*2, j*2+1); 32 lanes span one 512B row
#pragma unroll
    for (int j = 0; j < 8; j++) {
        int g = __shfl(sidx, j * 2 + half);
        bufA[j] = *(const f32x4*)(x + (long long)g * D + l31 * 4);
    }
#pragma unroll
    for (int j = 0; j < 8; j++) {
        int g = __shfl(didx, j * 2 + half);
        bufD[j] = *(const f32x4*)(x + (long long)g * D + l31 * 4);
    }

    // consume src: convert + write my chunk
#pragma unroll
    for (int j = 0; j < 8; j++) {
        f32x4 v = bufA[j];
        bf16x4 hv = { (bf16_t)v.x, (bf16_t)v.y, (bf16_t)v.z, (bf16_t)v.w };
        *(bf16x4*)&Ab[swz(r0 + j * 2 + half, l31 * 4)] = hv;
    }
    // issue ea streams into freed bufA (cover: barrier + phase q0)
#pragma unroll
    for (int j = 0; j < 8; j++) {
        int e = min(e0 + r0 + j * 2 + half, E - 1);
        bufA[j] = *(const f32x4*)(ea + (long long)e * D + l31 * 4);
    }
    // write B slice 0
#pragma unroll
    for (int j = 0; j < 8; j++)
        *(bf16x8*)&Bb[swz(j * 16 + brow_t, bslot)] = bnext[j];

    f32x4 acc[8];
#pragma unroll
    for (int n = 0; n < 8; n++) acc[n] = (f32x4){0.f, 0.f, 0.f, 0.f};

    float bias1[8], bias2[8];

    __syncthreads();

    // ---- phases q: A = {src, ea, dst, h}; B slices {0, 2, 1, 3} ----
#pragma unroll
    for (int q = 0; q < 4; q++) {
        if (q < 3) {
            const int snext = (q == 0) ? 2 : (q == 1) ? 1 : 3;
            const bf16_t* base = ws + snext * 16384;
#pragma unroll
            for (int j = 0; j < 8; j++)
                bnext[j] = *(const bf16x8*)(base + (j * 16 + brow_t) * 128 + bslot);
        }
        if (q == 1) {
#pragma unroll
            for (int n = 0; n < 8; n++) bias1[n] = b1[n*16 + col0];
        }
        if (q == 2) {
#pragma unroll
            for (int n = 0; n < 8; n++) bias2[n] = b2[n*16 + col0];
        }

        // MFMA for this phase (A from my LDS chunk)
#pragma unroll
        for (int kk = 0; kk < 4; kk++) {
            bf16x8 a = *(const bf16x8*)&Ab[swz(r0 + col0, kk*32 + krow*8)];
#pragma unroll
            for (int n = 0; n < 8; n++) {
                bf16x8 b = *(const bf16x8*)&Bb[swz(n*16 + col0, kk*32 + krow*8)];
                acc[n] = __builtin_amdgcn_mfma_f32_16x16x32_bf16(a, b, acc[n], 0, 0, 0);
            }
        }

        // chunk update for next phase (wave-private; per-wave LDS ordering suffices)
        if (q == 0) {        // ea arrives -> chunk
#pragma unroll
            for (int j = 0; j < 8; j++) {
                f32x4 v = bufA[j];
                bf16x4 hv = { (bf16_t)v.x, (bf16_t)v.y, (bf16_t)v.z, (bf16_t)v.w };
                *(bf16x4*)&Ab[swz(r0 + j * 2 + half, l31 * 4)] = hv;
            }
        } else if (q == 1) { // dst (issued in prologue) -> chunk
#pragma unroll
            for (int j = 0; j < 8; j++) {
                f32x4 v = bufD[j];
                bf16x4 hv = { (bf16_t)v.x, (bf16_t)v.y, (bf16_t)v.z, (bf16_t)v.w };
                *(bf16x4*)&Ab[swz(r0 + j * 2 + half, l31 * 4)] = hv;
            }
        } else if (q == 2) { // h = relu(acc + b1) -> chunk; reset acc
#pragma unroll
            for (int n = 0; n < 8; n++)
#pragma unroll
                for (int ri = 0; ri < 4; ri++) {
                    float hv = fmaxf(acc[n][ri] + bias1[n], 0.f);
                    Ab[swz(r0 + krow*4 + ri, n*16 + col0)] = (bf16_t)hv;
                }
#pragma unroll
            for (int n = 0; n < 8; n++) acc[n] = (f32x4){0.f, 0.f, 0.f, 0.f};
        }

        // rotate weight slice (only block-wide sync)
        if (q < 3) {
            __syncthreads();
#pragma unroll
            for (int j = 0; j < 8; j++)
                *(bf16x8*)&Bb[swz(j * 16 + brow_t, bslot)] = bnext[j];
            __syncthreads();
        }
    }

    // ---- epilogue: out = relu(acc + b2) ----
#pragma unroll
    for (int n = 0; n < 8; n++)
#pragma unroll
        for (int ri = 0; ri < 4; ri++) {
            int e = e0 + r0 + krow*4 + ri;
            if (e < E) out[(long long)e * D + n*16 + col0] = fmaxf(acc[n][ri] + bias2[n], 0.f);
        }
}

extern "C" void kernel_launch(void* const* d_in, const int* in_sizes, int n_in,
                              void* d_out, int out_size, void* d_ws, size_t ws_size,
                              hipStream_t stream) {
    const float* x  = (const float*)d_in[0];
    const float* ea = (const float*)d_in[1];
    const int*   ei = (const int*)d_in[2];
    const float* W1 = (const float*)d_in[3];
    const float* b1 = (const float*)d_in[4];
    const float* W2 = (const float*)d_in[5];
    const float* b2 = (const float*)d_in[6];
    float* out = (float*)d_out;

    const int E = in_sizes[1] / D;

    bf16_t* wsl = (bf16_t*)d_ws;    // 4 slices x 128x128 bf16 = 128 KB

    prep_weights_kernel<<<256, 256, 0, stream>>>(W1, W2, wsl);

    int nblocks = (E + BM - 1) / BM;    // 6250 for E=400000
    fused_edge_mlp_kernel<<<nblocks, 256, 0, stream>>>(x, ea, ei, wsl, b1, b2, out, E);
}

// Round 8
// 152.974 us; speedup vs baseline: 1.2479x; 1.0492x over previous
//
#include <hip/hip_runtime.h>
#include <hip/hip_bf16.h>

typedef __bf16 bf16_t;
typedef __bf16 bf16x8 __attribute__((ext_vector_type(8)));
typedef __bf16 bf16x4 __attribute__((ext_vector_type(4)));
typedef float  f32x4  __attribute__((ext_vector_type(4)));

#define D  128
#define BM 128  // 4 waves x 32 rows

// LDS element-index swizzle: XOR multiples of 8 elems (16B) keep 8-elem groups intact.
__device__ __forceinline__ int swz(int r, int c) {
    return (r * D + c) ^ ((r & 7) << 3);
}

// Fused prep: blocks [0,3125) convert x -> bf16 (8 elems/thread);
// blocks [3125,3381) build 4 slice-major transposed weight tiles.
__global__ void prep_kernel(const float* __restrict__ W1,
                            const float* __restrict__ W2,
                            const float* __restrict__ x,
                            bf16_t* __restrict__ ws,
                            bf16_t* __restrict__ xh) {
    int b = blockIdx.x;
    if (b < 3125) {                     // 3125*256*8 = 6,400,000 = 50000*128
        int t = b * 256 + threadIdx.x;
        f32x4 lo = *(const f32x4*)(x + t * 8);
        f32x4 hi = *(const f32x4*)(x + t * 8 + 4);
        bf16x8 v = { (bf16_t)lo.x,(bf16_t)lo.y,(bf16_t)lo.z,(bf16_t)lo.w,
                     (bf16_t)hi.x,(bf16_t)hi.y,(bf16_t)hi.z,(bf16_t)hi.w };
        *(bf16x8*)(xh + t * 8) = v;
    } else {                            // 256 blocks * 256 = 65536 weight elems
        int t = (b - 3125) * 256 + threadIdx.x;
        int s = t >> 14, r = t & 16383;
        int n = r >> 7, k = r & 127;
        float v = (s < 3) ? W1[(s * 128 + k) * 128 + n] : W2[k * 128 + n];
        ws[t] = (bf16_t)v;
    }
}

__global__ __launch_bounds__(256, 2)
void fused_edge_mlp_kernel(const bf16_t* __restrict__ xh,
                           const float* __restrict__ ea,
                           const int* __restrict__ ei,
                           const bf16_t* __restrict__ ws,
                           const float* __restrict__ b1,
                           const float* __restrict__ b2,
                           float* __restrict__ out,
                           int E) {
    __shared__ __align__(16) bf16_t Ab[BM * D];   // 32 KB: A/H tile, wave-private 32-row chunks
    __shared__ __align__(16) bf16_t Bb[D * D];    // 32 KB: current weight slice

    const int tid  = threadIdx.x;
    const int lane = tid & 63;
    const int wv   = tid >> 6;
    const int col0 = lane & 15;
    const int krow = lane >> 4;       // 0..3
    const int l31  = lane & 31;
    const int half = lane >> 5;
    const int e0   = blockIdx.x * BM;
    const int r0   = wv * 32;         // wave's first local row

    // lane l31 holds edge indices for local row l31 of this wave's chunk
    const int erI  = min(e0 + r0 + l31, E - 1);
    const int sidx = ei[erI];
    const int didx = ei[E + erI];

    // bf16 gather geometry: instr j covers rows j*4+gr, 16 lanes x 16B = 256B/row
    const int gr = lane >> 4;             // 0..3
    const int gc = (lane & 15) * 8;       // element offset in row

    // B staging: wave-instr j covers 4 consecutive rows = 1KB contiguous
    const int brow_t = tid >> 4;          // 0..15
    const int bslot  = (tid & 15) * 8;

    bf16x8 bufS[8], bufD[8], bnext[8];
    f32x4  eabuf[16];

    // ---- prologue: B slice0 + src gathers + dst gathers (all bf16, 256B segments) ----
#pragma unroll
    for (int j = 0; j < 8; j++)
        bnext[j] = *(const bf16x8*)(ws + (j * 16 + brow_t) * 128 + bslot);
#pragma unroll
    for (int j = 0; j < 8; j++) {
        int g = __shfl(sidx, j * 4 + gr);
        bufS[j] = *(const bf16x8*)(xh + g * D + gc);
    }
#pragma unroll
    for (int j = 0; j < 8; j++) {
        int g = __shfl(didx, j * 4 + gr);
        bufD[j] = *(const bf16x8*)(xh + g * D + gc);
    }
    float bias1[8], bias2[8];
#pragma unroll
    for (int n = 0; n < 8; n++) { bias1[n] = b1[n*16 + col0]; bias2[n] = b2[n*16 + col0]; }

    // write src chunk (waits only on bufS), then B0
#pragma unroll
    for (int j = 0; j < 8; j++)
        *(bf16x8*)&Ab[swz(r0 + j * 4 + gr, gc)] = bufS[j];
#pragma unroll
    for (int j = 0; j < 8; j++)
        *(bf16x8*)&Bb[swz(j * 16 + brow_t, bslot)] = bnext[j];

    f32x4 acc[2][8];
#pragma unroll
    for (int m = 0; m < 2; m++)
#pragma unroll
        for (int n = 0; n < 8; n++) acc[m][n] = (f32x4){0.f, 0.f, 0.f, 0.f};

    __syncthreads();

    // ---- phases q: A = {src, dst, ea, h}; B slices {0,1,2,3} ----
#pragma unroll
    for (int q = 0; q < 4; q++) {
        // prefetch next weight slice (L2-hot, hidden under MFMA)
        if (q < 3) {
            const bf16_t* base = ws + (q + 1) * 16384;
#pragma unroll
            for (int j = 0; j < 8; j++)
                bnext[j] = *(const bf16x8*)(base + (j * 16 + brow_t) * 128 + bslot);
        }
        // issue ea streams at q0 (consumed after q1 -> ~2 phases of cover)
        if (q == 0) {
#pragma unroll
            for (int j = 0; j < 16; j++) {
                int e = min(e0 + r0 + j * 2 + half, E - 1);
                eabuf[j] = *(const f32x4*)(ea + e * D + l31 * 4);
            }
        }

        // MFMA for this phase
#pragma unroll
        for (int kk = 0; kk < 4; kk++) {
            bf16x8 a0 = *(const bf16x8*)&Ab[swz(r0 +      col0, kk*32 + krow*8)];
            bf16x8 a1 = *(const bf16x8*)&Ab[swz(r0 + 16 + col0, kk*32 + krow*8)];
#pragma unroll
            for (int n = 0; n < 8; n++) {
                bf16x8 b = *(const bf16x8*)&Bb[swz(n*16 + col0, kk*32 + krow*8)];
                acc[0][n] = __builtin_amdgcn_mfma_f32_16x16x32_bf16(a0, b, acc[0][n], 0, 0, 0);
                acc[1][n] = __builtin_amdgcn_mfma_f32_16x16x32_bf16(a1, b, acc[1][n], 0, 0, 0);
            }
        }

        // chunk update for next phase (wave-private; per-wave LDS ordering suffices)
        if (q == 0) {        // dst (prologue-issued) -> chunk
#pragma unroll
            for (int j = 0; j < 8; j++)
                *(bf16x8*)&Ab[swz(r0 + j * 4 + gr, gc)] = bufD[j];
        } else if (q == 1) { // ea arrives -> convert -> chunk
#pragma unroll
            for (int j = 0; j < 16; j++) {
                f32x4 v = eabuf[j];
                bf16x4 hv = { (bf16_t)v.x, (bf16_t)v.y, (bf16_t)v.z, (bf16_t)v.w };
                *(bf16x4*)&Ab[swz(r0 + j * 2 + half, l31 * 4)] = hv;
            }
        } else if (q == 2) { // h = relu(acc + b1) -> chunk; reset acc
#pragma unroll
            for (int m = 0; m < 2; m++)
#pragma unroll
                for (int n = 0; n < 8; n++)
#pragma unroll
                    for (int ri = 0; ri < 4; ri++) {
                        float hv = fmaxf(acc[m][n][ri] + bias1[n], 0.f);
                        Ab[swz(r0 + m*16 + krow*4 + ri, n*16 + col0)] = (bf16_t)hv;
                    }
#pragma unroll
            for (int m = 0; m < 2; m++)
#pragma unroll
                for (int n = 0; n < 8; n++) acc[m][n] = (f32x4){0.f, 0.f, 0.f, 0.f};
        }

        // rotate weight slice (only block-wide sync)
        if (q < 3) {
            __syncthreads();
#pragma unroll
            for (int j = 0; j < 8; j++)
                *(bf16x8*)&Bb[swz(j * 16 + brow_t, bslot)] = bnext[j];
            __syncthreads();
        }
    }

    // ---- epilogue: out = relu(acc + b2) ----
#pragma unroll
    for (int m = 0; m < 2; m++)
#pragma unroll
        for (int n = 0; n < 8; n++)
#pragma unroll
            for (int ri = 0; ri < 4; ri++) {
                int e = e0 + r0 + m*16 + krow*4 + ri;
                if (e < E) out[e * D + n*16 + col0] = fmaxf(acc[m][n][ri] + bias2[n], 0.f);
            }
}

extern "C" void kernel_launch(void* const* d_in, const int* in_sizes, int n_in,
                              void* d_out, int out_size, void* d_ws, size_t ws_size,
                              hipStream_t stream) {
    const float* x  = (const float*)d_in[0];
    const float* ea = (const float*)d_in[1];
    const int*   ei = (const int*)d_in[2];
    const float* W1 = (const float*)d_in[3];
    const float* b1 = (const float*)d_in[4];
    const float* W2 = (const float*)d_in[5];
    const float* b2 = (const float*)d_in[6];
    float* out = (float*)d_out;

    const int E = in_sizes[1] / D;      // 400000
    const int N = in_sizes[0] / D;      // 50000

    bf16_t* wsl = (bf16_t*)d_ws;                 // 128 KB: 4 slice-major weight tiles
    bf16_t* xh  = (bf16_t*)d_ws + 4 * 16384;     // 12.8 MB: x in bf16

    const int xblocks = (N * D) / (256 * 8);     // 3125
    prep_kernel<<<xblocks + 256, 256, 0, stream>>>(W1, W2, x, wsl, xh);

    int nblocks = (E + BM - 1) / BM;             // 3125
    fused_edge_mlp_kernel<<<nblocks, 256, 0, stream>>>(xh, ea, ei, wsl, b1, b2, out, E);
}